// Round 4
// baseline (45.397 us; speedup 1.0000x reference)
//
#include <hip/hip_runtime.h>

// YOLO loss: preds/targets (N,7,7,2*(5+20)) fp32 -> scalar fp32.
// S=7, B=2, C=20, LAMBDA_NOOBJ=0.5, EPS=1e-9, divide by N at the end.
//
// R4: drop LDS staging entirely. Direct per-thread float2 loads (cell base =
// cell*200B, 8B-aligned). Every 128B line is fetched once (unused 76B gap per
// cell never covers a full line); L1 absorbs the intra-wave scatter since one
// wave's 64 consecutive cells span a contiguous 25.6KB region. No barriers,
// no LDS cap -> ~16-20 waves/CU of pure TLP. Partials to d_ws, tiny final
// reduce kernel (R3's atomic-chain fix retained).

#define NPC 50          // floats per cell per tensor = B*(5+C)
#define TPB 256

__device__ __forceinline__ float iou_xywh(float px, float py, float pw, float ph,
                                          float tx, float ty, float tw, float th) {
    float ax1 = px - pw * 0.5f, ay1 = py - ph * 0.5f;
    float ax2 = px + pw * 0.5f, ay2 = py + ph * 0.5f;
    float bx1 = tx - tw * 0.5f, by1 = ty - th * 0.5f;
    float bx2 = tx + tw * 0.5f, by2 = ty + th * 0.5f;
    float iw = fmaxf(fminf(ax2, bx2) - fmaxf(ax1, bx1), 0.0f);
    float ih = fmaxf(fminf(ay2, by2) - fmaxf(ay1, by1), 0.0f);
    float inter = iw * ih;
    float uni = pw * ph + tw * th - inter;
    return inter / (uni + 1e-9f);
}

__global__ __launch_bounds__(TPB) void yolo_cell_kernel(
        const float* __restrict__ preds,
        const float* __restrict__ targets,
        float* __restrict__ part,
        int ncells) {
    __shared__ float wsum[TPB / 64];

    const int tid = threadIdx.x;
    const int cell_idx = blockIdx.x * TPB + tid;

    float cell = 0.0f;
    if (cell_idx < ncells) {
        const float2* cp2 = (const float2*)(preds + (long long)cell_idx * NPC);
        const float2* ct2 = (const float2*)(targets + (long long)cell_idx * NPC);

        float2 p01 = cp2[0];            // p0,p1
        float2 p23 = cp2[1];            // p2,p3
        float2 t01 = ct2[0];
        float2 t23 = ct2[1];
        float2 t4_ = ct2[2];            // t4, t5(unused)
        float2 pA = cp2[12];            // p24(unused), p25
        float2 pB = cp2[13];            // p26, p27
        float2 pC = cp2[14];            // p28, p29(unused)
        float2 tA = ct2[12];
        float2 tB = ct2[13];
        float2 tC = ct2[14];

        float iou0 = iou_xywh(p01.x, p01.y, p23.x, p23.y,
                              t01.x, t01.y, t23.x, t23.y);
        float iou1 = iou_xywh(pA.y, pB.x, pB.y, pC.x,
                              tA.y, tB.x, tB.y, tC.x);
        int best = (iou1 > iou0) ? 1 : 0;   // argmax, first-max tie-break
        bool has_obj = (t4_.x > 0.0f) || (tC.y > 0.0f);

        float dx, dy;
        if (best == 0) { dx = p01.x - t01.x; dy = p01.y - t01.y; }
        else           { dx = pA.y - tA.y;   dy = pB.x - tB.x;   }
        float dxy = dx * dx + dy * dy;
        cell = has_obj ? dxy : 0.0f;

        // classes of b = B-1 = 1: channels [30..49] = float2 idx [15..24]
        float csum = 0.0f;
        float bv = -1e30f;   // running max of tc (strict > keeps first max)
        float pg = 0.0f;     // pc at argmax(tc)
        #pragma unroll
        for (int j = 0; j < 10; ++j) {
            float2 tv = ct2[15 + j];
            float2 pv = cp2[15 + j];
            float d0 = pv.x - tv.x;
            float d1 = pv.y - tv.y;
            csum += d0 * d0 + d1 * d1;
            if (tv.x > bv) { bv = tv.x; pg = pv.x; }
            if (tv.y > bv) { bv = tv.y; pg = pv.y; }
        }
        cell += csum;

        // conf term: (iou_b * p_gt - iou_b)^2, weight 1 at best else 0.5
        float f = pg - 1.0f;
        float f2 = f * f;
        float e0 = iou0 * iou0 * f2;
        float e1 = iou1 * iou1 * f2;
        cell += (best == 0) ? e0 : 0.5f * e0;
        cell += (best == 1) ? e1 : 0.5f * e1;
    }

    // ---- block reduction: wave64 shuffle -> LDS partials -> one store ----
    float v = cell;
    #pragma unroll
    for (int off = 32; off >= 1; off >>= 1) v += __shfl_down(v, off);
    const int wave = tid >> 6;
    const int lane = tid & 63;
    if (lane == 0) wsum[wave] = v;
    __syncthreads();
    if (tid == 0) {
        float s = 0.0f;
        #pragma unroll
        for (int w = 0; w < TPB / 64; ++w) s += wsum[w];
        part[blockIdx.x] = s;           // distinct address per block: no chain
    }
}

__global__ __launch_bounds__(256) void yolo_final_kernel(
        const float* __restrict__ part, float* __restrict__ out,
        int nblk, float invN) {
    __shared__ float wsum[4];
    const int tid = threadIdx.x;
    float s = 0.0f;
    for (int i = tid; i < nblk; i += 256) s += part[i];
    #pragma unroll
    for (int off = 32; off >= 1; off >>= 1) s += __shfl_down(s, off);
    if ((tid & 63) == 0) wsum[tid >> 6] = s;
    __syncthreads();
    if (tid == 0) {
        out[0] = (wsum[0] + wsum[1] + wsum[2] + wsum[3]) * invN;
    }
}

extern "C" void kernel_launch(void* const* d_in, const int* in_sizes, int n_in,
                              void* d_out, int out_size, void* d_ws, size_t ws_size,
                              hipStream_t stream) {
    const float* preds = (const float*)d_in[0];
    const float* targets = (const float*)d_in[1];
    float* out = (float*)d_out;
    float* part = (float*)d_ws;                     // nblk floats of scratch

    const int ncells = in_sizes[0] / NPC;          // N*S*S = 401408
    const int N = ncells / 49;                      // S*S = 49
    const int nblk = (ncells + TPB - 1) / TPB;      // 1568 (exact)

    yolo_cell_kernel<<<nblk, TPB, 0, stream>>>(preds, targets, part, ncells);
    yolo_final_kernel<<<1, 256, 0, stream>>>(part, out, nblk, 1.0f / (float)N);
}

// Round 5
// 31.097 us; speedup vs baseline: 1.4599x; 1.4599x over previous
//
#include <hip/hip_runtime.h>

// YOLO loss: preds/targets (N,7,7,2*(5+20)) fp32 -> scalar fp32.
// S=7, B=2, C=20, LAMBDA_NOOBJ=0.5, EPS=1e-9, divide by N at the end.
//
// R5: persistent single-wave blocks + double-buffered global_load_lds with
// COUNTED vmcnt (T3/T4). Tile = 64 cells = 25.6KB (both tensors); 2 buffers
// = 51.2KB static LDS -> 3 blocks/CU; block = 1 wave -> zero barriers.
// Loop: issue 28 loads for tile t+1, s_waitcnt vmcnt(28) (tile t done, t+1
// still in flight), compute tile t, swap. The memory pipe never drains.
// R4 lesson: per-thread scattered loads TA-split (~100 lines/instr) and cap
// at 2 TB/s -- coalesced staging is mandatory. R3 lesson: no same-address
// atomics; partials to d_ws + tiny final reduce.

#define NPC 50            // floats per cell per tensor
#define CPT 64            // cells per tile
#define TPB 64            // 1 wave per block
#define TILE_F (CPT * NPC)   // 3200 floats per tensor per tile
#define NCHUNK 28            // 12 w16 + 2 w4 per tensor, x2 tensors

typedef const __attribute__((address_space(1))) void gvoid_t;
typedef __attribute__((address_space(3))) void lvoid_t;

__device__ __forceinline__ float iou_xywh(float px, float py, float pw, float ph,
                                          float tx, float ty, float tw, float th) {
    float ax1 = px - pw * 0.5f, ay1 = py - ph * 0.5f;
    float ax2 = px + pw * 0.5f, ay2 = py + ph * 0.5f;
    float bx1 = tx - tw * 0.5f, by1 = ty - th * 0.5f;
    float bx2 = tx + tw * 0.5f, by2 = ty + th * 0.5f;
    float iw = fmaxf(fminf(ax2, bx2) - fmaxf(ax1, bx1), 0.0f);
    float ih = fmaxf(fminf(ay2, by2) - fmaxf(ay1, by1), 0.0f);
    float inter = iw * ih;
    float uni = pw * ph + tw * th - inter;
    return inter / (uni + 1e-9f);
}

// Full per-cell loss. cp2/ct2 point at one cell's 50 floats (8B-aligned).
__device__ __forceinline__ float cell_loss(const float2* __restrict__ cp2,
                                           const float2* __restrict__ ct2) {
    float2 p01 = cp2[0];            // p0,p1
    float2 p23 = cp2[1];            // p2,p3
    float2 t01 = ct2[0];
    float2 t23 = ct2[1];
    float2 t4_ = ct2[2];            // t4, t5(unused)
    float2 pA = cp2[12];            // p24(unused), p25
    float2 pB = cp2[13];            // p26, p27
    float2 pC = cp2[14];            // p28, p29(unused)
    float2 tA = ct2[12];
    float2 tB = ct2[13];
    float2 tC = ct2[14];

    float iou0 = iou_xywh(p01.x, p01.y, p23.x, p23.y,
                          t01.x, t01.y, t23.x, t23.y);
    float iou1 = iou_xywh(pA.y, pB.x, pB.y, pC.x,
                          tA.y, tB.x, tB.y, tC.x);
    int best = (iou1 > iou0) ? 1 : 0;   // argmax, first-max tie-break
    bool has_obj = (t4_.x > 0.0f) || (tC.y > 0.0f);

    float dx, dy;
    if (best == 0) { dx = p01.x - t01.x; dy = p01.y - t01.y; }
    else           { dx = pA.y - tA.y;   dy = pB.x - tB.x;   }
    float cell = has_obj ? (dx * dx + dy * dy) : 0.0f;

    // classes of b = B-1 = 1: channels [30..49] = float2 idx [15..24]
    float csum = 0.0f;
    float bv = -1e30f;   // running max of tc (strict > keeps first max)
    float pg = 0.0f;     // pc at argmax(tc)
    #pragma unroll
    for (int j = 0; j < 10; ++j) {
        float2 tv = ct2[15 + j];
        float2 pv = cp2[15 + j];
        float d0 = pv.x - tv.x;
        float d1 = pv.y - tv.y;
        csum += d0 * d0 + d1 * d1;
        if (tv.x > bv) { bv = tv.x; pg = pv.x; }
        if (tv.y > bv) { bv = tv.y; pg = pv.y; }
    }
    cell += csum;

    // conf term: (iou_b * p_gt - iou_b)^2, weight 1 at best else 0.5
    float f = pg - 1.0f;
    float f2 = f * f;
    float e0 = iou0 * iou0 * f2;
    float e1 = iou1 * iou1 * f2;
    cell += (best == 0) ? e0 : 0.5f * e0;
    cell += (best == 1) ? e1 : 0.5f * e1;
    return cell;
}

__global__ __launch_bounds__(TPB) void yolo_cell_kernel(
        const float* __restrict__ preds,
        const float* __restrict__ targets,
        float* __restrict__ part,
        int ncells, int nb) {
    __shared__ float lbuf[2][2 * TILE_F];   // [buf][preds|targets] = 51.2 KB

    const int lane = threadIdx.x;           // 0..63, one wave
    const int bid = blockIdx.x;
    const int ntiles = ncells / CPT;

    float acc = 0.0f;

    // Stage one tile (both tensors) into lbuf[b]: 24x w16 + 4x w4 chunks,
    // linear LDS (global_load_lds writes base + lane*width).
    auto stage = [&](int b, int t) {
        const float* ps = preds + (long long)t * TILE_F;
        const float* ts = targets + (long long)t * TILE_F;
        float* lp = lbuf[b];
        float* lt = lbuf[b] + TILE_F;
        #pragma unroll
        for (int c = 0; c < 12; ++c)
            __builtin_amdgcn_global_load_lds((gvoid_t*)(ps + c * 256 + lane * 4),
                                             (lvoid_t*)(lp + c * 256), 16, 0, 0);
        #pragma unroll
        for (int c = 0; c < 2; ++c)
            __builtin_amdgcn_global_load_lds((gvoid_t*)(ps + 3072 + c * 64 + lane),
                                             (lvoid_t*)(lp + 3072 + c * 64), 4, 0, 0);
        #pragma unroll
        for (int c = 0; c < 12; ++c)
            __builtin_amdgcn_global_load_lds((gvoid_t*)(ts + c * 256 + lane * 4),
                                             (lvoid_t*)(lt + c * 256), 16, 0, 0);
        #pragma unroll
        for (int c = 0; c < 2; ++c)
            __builtin_amdgcn_global_load_lds((gvoid_t*)(ts + 3072 + c * 64 + lane),
                                             (lvoid_t*)(lt + 3072 + c * 64), 4, 0, 0);
    };

    // ---- software pipeline: prologue stage, counted-vmcnt steady state ----
    if (bid < ntiles) stage(0, bid);
    int b = 0;
    for (int t = bid; t < ntiles; t += nb) {
        const int tn = t + nb;
        if (tn < ntiles) {
            stage(b ^ 1, tn);
            // wait only for tile t's 28 loads; tn's 28 stay in flight
            asm volatile("s_waitcnt vmcnt(28)" ::: "memory");
        } else {
            asm volatile("s_waitcnt vmcnt(0)" ::: "memory");
        }
        __builtin_amdgcn_sched_barrier(0);

        const float2* cp2 = (const float2*)(lbuf[b] + lane * NPC);
        const float2* ct2 = (const float2*)(lbuf[b] + TILE_F + lane * NPC);
        acc += cell_loss(cp2, ct2);
        b ^= 1;
    }

    // ---- remainder cells (ncells % 64; zero for this problem size) ----
    const int rem0 = ntiles * CPT;
    if (rem0 < ncells && bid == nb - 1) {
        for (int i = rem0 + lane; i < ncells; i += TPB) {
            const float2* cp2 = (const float2*)(preds + (long long)i * NPC);
            const float2* ct2 = (const float2*)(targets + (long long)i * NPC);
            acc += cell_loss(cp2, ct2);
        }
    }

    // ---- wave reduction, one plain store per block (no atomics) ----
    #pragma unroll
    for (int off = 32; off >= 1; off >>= 1) acc += __shfl_down(acc, off);
    if (lane == 0) part[bid] = acc;
}

__global__ __launch_bounds__(256) void yolo_final_kernel(
        const float* __restrict__ part, float* __restrict__ out,
        int nblk, float invN) {
    __shared__ float wsum[4];
    const int tid = threadIdx.x;
    float s = 0.0f;
    for (int i = tid; i < nblk; i += 256) s += part[i];
    #pragma unroll
    for (int off = 32; off >= 1; off >>= 1) s += __shfl_down(s, off);
    if ((tid & 63) == 0) wsum[tid >> 6] = s;
    __syncthreads();
    if (tid == 0) {
        out[0] = (wsum[0] + wsum[1] + wsum[2] + wsum[3]) * invN;
    }
}

extern "C" void kernel_launch(void* const* d_in, const int* in_sizes, int n_in,
                              void* d_out, int out_size, void* d_ws, size_t ws_size,
                              hipStream_t stream) {
    const float* preds = (const float*)d_in[0];
    const float* targets = (const float*)d_in[1];
    float* out = (float*)d_out;
    float* part = (float*)d_ws;                 // nb floats of scratch

    const int ncells = in_sizes[0] / NPC;       // N*S*S = 401408
    const int N = ncells / 49;                  // S*S = 49
    const int nb = 768;                          // 3 blocks/CU x 256 CU

    yolo_cell_kernel<<<nb, TPB, 0, stream>>>(preds, targets, part, ncells, nb);
    yolo_final_kernel<<<1, 256, 0, stream>>>(part, out, nb, 1.0f / (float)N);
}